// Round 22
// baseline (43.961 us; speedup 1.0000x reference)
//
#include <hip/hip_runtime.h>

#define DISP_W 1.0f
#define MAT_W  0.1f
#define CD_W   0.5f

typedef _Float16 half8 __attribute__((ext_vector_type(8)));
typedef float f32x16 __attribute__((ext_vector_type(16)));
typedef float f32x4  __attribute__((ext_vector_type(4)));

constexpr int BB = 4;           // batch
constexpr int NN = 8192;        // points per cloud
constexpr int THREADS = 256;    // 4 waves
constexpr int IB = 256;         // pred rows per block = 4 waves x 64 (2 frags/wave)
constexpr int JR = 512;         // target cols per LDS stage (8KB hi + 8KB lo)
constexpr int NSTAGE = 4;       // stages per block
constexpr int JB = JR * NSTAGE; // 2048 cols per block
constexpr int NIB = NN / IB;    // 32
constexpr int NJQ = NN / JB;    // 4
constexpr int NCHUNK = JR / 32; // 16
constexpr int NPT2 = BB * NN;   // 32768 points per cloud
constexpr int GRID = BB * NIB * NJQ;   // 512 = 2 blocks/CU, one round
constexpr int RSTRIDE = 36;     // epilogue scratch row stride in floats (144 B)
constexpr int NBF = NPT2 / 256; // build_frags blocks = 128
constexpr int PFT = JR / THREADS;      // 2 prefetch half8 per array per thread

// Verified K=16 MFMA layout (rounds 3-21, absmax 0.0):
//  A: [xh yh zh  xh yh zh  xl yl | zl ch cl 1 1 0 0 0]          (pred pos)
//  B: [uxh uyh uzh uxl uyl uzl uxh uyh | uzh 1 1 ch cl 0 0 0]   (u = -2*target pos)
// dot = -2 a.b (hi/lo compensated) + ca + cb = |a-b|^2 (~f32 precision).
// ONE pass: row-mins (over j) = pred->target, col-mins (over i) = target->pred.

__global__ __launch_bounds__(256)
void build_frags(const float* __restrict__ pred_disp,
                 const float* __restrict__ target_disp,
                 const float* __restrict__ tmpl,
                 half8* __restrict__ fragA,      // [b][n][2] (hi,lo)  pred
                 half8* __restrict__ fragBhi,    // [b][n]             target
                 half8* __restrict__ fragBlo,
                 float* __restrict__ dsum_ws,    // [NBF] per-block |d| partials
                 float* __restrict__ out)
{
    int p = blockIdx.x * 256 + threadIdx.x;     // 0..32767
    if (p == 0) out[0] = 0.0f;                  // deterministic re-zero each call
    int b = p >> 13;
    int n = p & (NN - 1);

    const float* pd = pred_disp   + (size_t)b * NN * 3;
    const float* td = target_disp + (size_t)b * NN * 3;
    const float* tp = tmpl        + (size_t)b * NN * 3;

    int n3 = n * 3;
    float pdx = pd[n3 + 0], pdy = pd[n3 + 1], pdz = pd[n3 + 2];
    float tdx = td[n3 + 0], tdy = td[n3 + 1], tdz = td[n3 + 2];
    float t0 = tp[n3 + 0], t1 = tp[n3 + 1], t2 = tp[n3 + 2];

    // fused disp L1 partial
    float s = fabsf(pdx - tdx) + fabsf(pdy - tdy) + fabsf(pdz - tdz);

    const _Float16 one  = (_Float16)1.0f;
    const _Float16 zero = (_Float16)0.0f;

    // pred pos -> A fragment
    {
        float x = t0 + pdx, y = t1 + pdy, z = t2 + pdz;
        float cc = fmaf(x, x, fmaf(y, y, z * z));
        _Float16 xh = (_Float16)x;  _Float16 xl = (_Float16)(x - (float)xh);
        _Float16 yh = (_Float16)y;  _Float16 yl = (_Float16)(y - (float)yh);
        _Float16 zh = (_Float16)z;  _Float16 zl = (_Float16)(z - (float)zh);
        _Float16 ch = (_Float16)cc; _Float16 cl = (_Float16)(cc - (float)ch);
        half8 aHi = {xh, yh, zh, xh, yh, zh, xl, yl};
        half8 aLo = {zl, ch, cl, one, one, zero, zero, zero};
        fragA[(size_t)p * 2 + 0] = aHi;
        fragA[(size_t)p * 2 + 1] = aLo;
    }

    // target pos -> B fragment
    {
        float x = t0 + tdx, y = t1 + tdy, z = t2 + tdz;
        float cc = fmaf(x, x, fmaf(y, y, z * z));
        float ux = -2.0f * x, uy = -2.0f * y, uz = -2.0f * z;
        _Float16 uxh = (_Float16)ux; _Float16 uxl = (_Float16)(ux - (float)uxh);
        _Float16 uyh = (_Float16)uy; _Float16 uyl = (_Float16)(uy - (float)uyh);
        _Float16 uzh = (_Float16)uz; _Float16 uzl = (_Float16)(uz - (float)uzh);
        _Float16 ch = (_Float16)cc; _Float16 cl = (_Float16)(cc - (float)ch);
        half8 bHi = {uxh, uyh, uzh, uxl, uyl, uzl, uxh, uyh};
        half8 bLo = {uzh, one, one, ch, cl, zero, zero, zero};
        fragBhi[p] = bHi;
        fragBlo[p] = bLo;
    }

    // block-reduce s -> dsum_ws[blockIdx] (indexed write, no atomics/zeroing)
    for (int off = 32; off > 0; off >>= 1)
        s += __shfl_down(s, off, 64);
    __shared__ float ws4[4];
    int lane = threadIdx.x & 63, w = threadIdx.x >> 6;
    if (lane == 0) ws4[w] = s;
    __syncthreads();
    if (threadIdx.x == 0)
        dsum_ws[blockIdx.x] = ws4[0] + ws4[1] + ws4[2] + ws4[3];
}

__global__ __launch_bounds__(THREADS, 2)   // 256-reg budget: VGPR-form accumulators
void chamfer_mfma(const half8* __restrict__ fragA,
                  const half8* __restrict__ fragBhi,
                  const half8* __restrict__ fragBlo,
                  float* __restrict__ rowpart,
                  float* __restrict__ colpart)
{
    // 48 KB LDS: 16 KB staging + 32 KB colw (colw reused as transpose scratch)
    __shared__ __align__(16) char lds_raw[49152];
    half8* sBhi = (half8*)lds_raw;             // 8 KB
    half8* sBlo = (half8*)(lds_raw + 8192);    // 8 KB
    float* colw = (float*)(lds_raw + 16384);   // 4 waves x 2048 cols = 32 KB

    int bx = blockIdx.x;
    int jq   = bx & (NJQ - 1);
    int iBlk = (bx >> 2) & (NIB - 1);
    int b    = bx >> 7;

    const int tid  = threadIdx.x;
    const int lane = tid & 63;
    const int w    = tid >> 6;
    const int hi   = lane >> 5;
    const int li   = lane & 31;

    // ---- two A fragments per wave (pred rows i0, i0+32), loaded once ----
    int i0 = iBlk * IB + w * 64 + li;
    size_t aBase = (size_t)b * NN;
    half8 aF0 = fragA[(aBase + i0) * 2 + hi];
    half8 aF1 = fragA[(aBase + i0 + 32) * 2 + hi];

    size_t pB = (size_t)b * NN + (size_t)jq * JB;
    const half8* gHi = fragBhi + pB;
    const half8* gLo = fragBlo + pB;

    f32x16 kZero = {0.f,0.f,0.f,0.f, 0.f,0.f,0.f,0.f, 0.f,0.f,0.f,0.f, 0.f,0.f,0.f,0.f};
    float rm0[16], rm1[16];
    #pragma unroll
    for (int r = 0; r < 16; ++r) { rm0[r] = 1.0e30f; rm1[r] = 1.0e30f; }

    // ---- T14 pipeline: prefetch stage s+1 to regs during stage-s compute ----
    half8 pfHi[PFT], pfLo[PFT];
    #pragma unroll
    for (int t = 0; t < PFT; ++t) {
        pfHi[t] = gHi[t * THREADS + tid];
        pfLo[t] = gLo[t * THREADS + tid];
    }
    #pragma unroll
    for (int t = 0; t < PFT; ++t) {
        sBhi[t * THREADS + tid] = pfHi[t];
        sBlo[t * THREADS + tid] = pfLo[t];
    }
    __syncthreads();

    for (int s = 0; s < NSTAGE; ++s) {
        if (s + 1 < NSTAGE) {
            const half8* srcHi = gHi + (size_t)(s + 1) * JR;
            const half8* srcLo = gLo + (size_t)(s + 1) * JR;
            #pragma unroll
            for (int t = 0; t < PFT; ++t) {
                pfHi[t] = srcHi[t * THREADS + tid];
                pfLo[t] = srcLo[t * THREADS + tid];
            }
        }

        const half8* baseB = hi ? sBlo : sBhi;
        const int cwBase = w * JB + s * JR;
        // 1 ds_read feeds 2 MFMAs; row fold = dual plain-fmin chains; col fold =
        // pairwise fmin + tree + shfl (col-min over this wave's 64 rows).
        #pragma unroll 4
        for (int c = 0; c < NCHUNK; ++c) {
            half8 b0 = baseB[c * 32 + li];
            f32x16 a0 = __builtin_amdgcn_mfma_f32_32x32x16_f16(aF0, b0, kZero, 0, 0, 0);
            f32x16 a1 = __builtin_amdgcn_mfma_f32_32x32x16_f16(aF1, b0, kZero, 0, 0, 0);
            #pragma unroll
            for (int r = 0; r < 16; ++r)
                rm0[r] = fminf(rm0[r], a0[r]);
            #pragma unroll
            for (int r = 0; r < 16; ++r)
                rm1[r] = fminf(rm1[r], a1[r]);
            // col-min for cols c*32..+31 over the wave's 64 rows
            float cv[16];
            #pragma unroll
            for (int r = 0; r < 16; ++r) cv[r] = fminf(a0[r], a1[r]);
            #pragma unroll
            for (int st = 8; st > 0; st >>= 1)
                #pragma unroll
                for (int r = 0; r < st; ++r) cv[r] = fminf(cv[r], cv[r + st]);
            float v = fminf(cv[0], __shfl_xor(cv[0], 32, 64));
            if (lane < 32) colw[cwBase + c * 32 + lane] = v;
        }
        __syncthreads();   // all waves done reading sB before overwrite

        if (s + 1 < NSTAGE) {
            #pragma unroll
            for (int t = 0; t < PFT; ++t) {
                sBhi[t * THREADS + tid] = pfHi[t];
                sBlo[t * THREADS + tid] = pfLo[t];
            }
            __syncthreads();
        }
    }

    // ---- col partials: combine 4 waves, indexed write (no atomics) ----
    size_t cpBase = ((size_t)b * NIB + iBlk) * NN + (size_t)jq * JB;
    for (int j = tid; j < JB; j += THREADS) {
        float v = fminf(fminf(colw[j], colw[JB + j]),
                        fminf(colw[2 * JB + j], colw[3 * JB + j]));
        colpart[cpBase + j] = v;
    }
    __syncthreads();   // colw free -> reuse as transpose scratch

    // ---- row epilogue: two per-wave LDS-transpose passes, coalesced stores ----
    float* scr = (float*)(lds_raw + 16384);
    int wbase = w * (32 * RSTRIDE);                 // per-wave 4608 B region
    int cbase = wbase + hi * 4 * RSTRIDE + li;
    size_t obase = ((size_t)b * NJQ + jq) * NN + (size_t)iBlk * IB + w * 64;

    // pass 0: rows i0 block
    #pragma unroll
    for (int r = 0; r < 16; ++r)
        scr[cbase + ((r & 3) + 8 * (r >> 2)) * RSTRIDE] = rm0[r];
    __syncthreads();
    {
        const f32x4* rp = (const f32x4*)&scr[wbase + (lane & 31) * RSTRIDE];
        f32x4 q0 = rp[0], q1 = rp[1], q2 = rp[2], q3 = rp[3];
        f32x4 q4 = rp[4], q5 = rp[5], q6 = rp[6], q7 = rp[7];
        f32x4 m4;
        #pragma unroll
        for (int k = 0; k < 4; ++k)
            m4[k] = fminf(fminf(fminf(q0[k], q1[k]), fminf(q2[k], q3[k])),
                          fminf(fminf(q4[k], q5[k]), fminf(q6[k], q7[k])));
        float m = fminf(fminf(m4[0], m4[1]), fminf(m4[2], m4[3]));
        if (lane < 32) rowpart[obase + lane] = m;
    }
    __syncthreads();

    // pass 1: rows i0+32 block
    #pragma unroll
    for (int r = 0; r < 16; ++r)
        scr[cbase + ((r & 3) + 8 * (r >> 2)) * RSTRIDE] = rm1[r];
    __syncthreads();
    {
        const f32x4* rp = (const f32x4*)&scr[wbase + (lane & 31) * RSTRIDE];
        f32x4 q0 = rp[0], q1 = rp[1], q2 = rp[2], q3 = rp[3];
        f32x4 q4 = rp[4], q5 = rp[5], q6 = rp[6], q7 = rp[7];
        f32x4 m4;
        #pragma unroll
        for (int k = 0; k < 4; ++k)
            m4[k] = fminf(fminf(fminf(q0[k], q1[k]), fminf(q2[k], q3[k])),
                          fminf(fminf(q4[k], q5[k]), fminf(q6[k], q7[k])));
        float m = fminf(fminf(m4[0], m4[1]), fminf(m4[2], m4[3]));
        if (lane < 32) rowpart[obase + 32 + lane] = m;
    }
}

__global__ __launch_bounds__(256)
void final_reduce(const float* __restrict__ pred_mat,
                  const float* __restrict__ target_mat,
                  const float* __restrict__ rowpart,
                  const float* __restrict__ colpart,
                  const float* __restrict__ dsum_ws,
                  float* __restrict__ out)
{
    int gtid = blockIdx.x * blockDim.x + threadIdx.x;
    int gstride = gridDim.x * blockDim.x;

    float msum = 0.0f;
    for (int t = gtid; t < NPT2; t += gstride) {
        int b = t >> 13;
        int i = t & (NN - 1);
        // pred->target: fold NJQ row partials
        const float* rp = rowpart + (size_t)b * NJQ * NN + i;
        float mr = 1.0e30f;
        #pragma unroll
        for (int jb = 0; jb < NJQ; ++jb)
            mr = fminf(mr, rp[(size_t)jb * NN]);
        msum += fmaxf(mr, 0.0f);
        // target->pred: fold NIB col partials
        const float* cp = colpart + (size_t)b * NIB * NN + i;
        float mc = 1.0e30f;
        #pragma unroll 8
        for (int ib = 0; ib < NIB; ++ib)
            mc = fminf(mc, cp[(size_t)ib * NN]);
        msum += fmaxf(mc, 0.0f);
    }

    float acc = msum * (CD_W / (float)(BB * NN));

    if (gtid < NBF)
        acc += dsum_ws[gtid] * (DISP_W / (float)(BB * NN * 3));

    if (gtid < 2 * BB) {
        float d = pred_mat[gtid] - target_mat[gtid];
        acc += d * d * (MAT_W / (float)(2 * BB));
    }

    for (int off = 32; off > 0; off >>= 1)
        acc += __shfl_down(acc, off, 64);

    __shared__ float wsum[4];
    if ((threadIdx.x & 63) == 0) wsum[threadIdx.x >> 6] = acc;
    __syncthreads();
    if (threadIdx.x == 0)
        atomicAdd(out, wsum[0] + wsum[1] + wsum[2] + wsum[3]);
}

extern "C" void kernel_launch(void* const* d_in, const int* in_sizes, int n_in,
                              void* d_out, int out_size, void* d_ws, size_t ws_size,
                              hipStream_t stream) {
    const float* pred_disp   = (const float*)d_in[0];
    const float* pred_mat    = (const float*)d_in[1];
    const float* target_disp = (const float*)d_in[2];
    const float* target_mat  = (const float*)d_in[3];
    const float* tmpl        = (const float*)d_in[4];

    // ws layout (all ws buffers written exactly once per call):
    //   fragA   : NPT2*2 half8 = 1 MB      (pred)
    //   fragBhi : NPT2   half8 = 512 KB    (target)
    //   fragBlo : NPT2   half8 = 512 KB
    //   rowpart : BB*NJQ*NN floats = 512 KB
    //   colpart : BB*NIB*NN floats = 4 MB
    //   dsum_ws : NBF floats
    half8* fragA   = (half8*)d_ws;
    half8* fragBhi = fragA + (size_t)NPT2 * 2;
    half8* fragBlo = fragBhi + NPT2;
    float* rowpart = (float*)(fragBlo + NPT2);
    float* colpart = rowpart + (size_t)BB * NJQ * NN;
    float* dsum_ws = colpart + (size_t)BB * NIB * NN;
    float* out = (float*)d_out;

    build_frags<<<NBF, 256, 0, stream>>>(pred_disp, target_disp, tmpl,
                                         fragA, fragBhi, fragBlo, dsum_ws, out);
    chamfer_mfma<<<GRID, THREADS, 0, stream>>>(fragA, fragBhi, fragBlo,
                                               rowpart, colpart);
    final_reduce<<<128, 256, 0, stream>>>(pred_mat, target_mat, rowpart, colpart,
                                          dsum_ws, out);
}

// Round 23
// 33.248 us; speedup vs baseline: 1.3222x; 1.3222x over previous
//
#include <hip/hip_runtime.h>

#define DISP_W 1.0f
#define MAT_W  0.1f
#define CD_W   0.5f

typedef _Float16 half8 __attribute__((ext_vector_type(8)));
typedef float f32x16 __attribute__((ext_vector_type(16)));
typedef float f32x4  __attribute__((ext_vector_type(4)));

constexpr int BB = 4;           // batch
constexpr int NN = 8192;        // points per cloud
constexpr int THREADS = 256;    // 4 waves
constexpr int IB = 256;         // A-rows per block = 4 waves x 64 (2 frags/wave)
constexpr int JR = 1024;        // B-cols per LDS stage
constexpr int NSTAGE = 2;       // pipelined stages per block (2048 cols)
constexpr int NIB = NN / IB;    // 32
constexpr int NJQ = NN / (JR * NSTAGE);    // 4 column quarters
constexpr int NCHUNK = JR / 32; // 32
constexpr int NPTS = 2 * BB * NN;          // 65536
constexpr int GRID = 2 * BB * NIB * NJQ;   // 1024
constexpr int RSTRIDE = 36;     // epilogue scratch row stride in floats (144 B)
constexpr int NBF = NPTS / 256; // build_frags blocks = 256
constexpr int PFT = JR / THREADS;          // 4 prefetch half8 per array per thread

// Verified K=16 MFMA layout (rounds 3-22, absmax 0.0):
//  A: [xh yh zh  xh yh zh  xl yl | zl ch cl 1 1 0 0 0]
//  B: [uxh uyh uzh uxl uyl uzl uxh uyh | uzh 1 1 ch cl 0 0 0]  (u = -2*pos)
// dot = -2 a.b (hi/lo compensated) + ca + cb = |a-b|^2 (~f32 precision).
//
// Champion configuration (r19, 33.1 us). Load-bearing pieces:
//  - __launch_bounds__(256,2): 256-reg budget keeps f32x16 MFMA accumulators
//    in VGPR-form (any <=168-reg budget triggers the AGPR split: +16
//    v_accvgpr_read per tile -- measured regressions r10/r12/r16/r18).
//  - dual plain-fmin chains: each fmin reads one accumulator operand in place
//    (min3 with two acc operands forces accvgpr moves -- r13 regression).
//  - 1 ds_read feeds 2 MFMAs (B-share): halves LDS pipe traffic (r14 win).
//  - T14 reg-prefetch: stage s+1 global loads issued before stage-s compute,
//    LDS write after barrier -- staging latency off critical path (r17 win).

__global__ __launch_bounds__(256)
void build_frags(const float* __restrict__ pred_disp,
                 const float* __restrict__ target_disp,
                 const float* __restrict__ tmpl,
                 half8* __restrict__ fragA,      // [cloud][b][n][2] (hi,lo)
                 half8* __restrict__ fragBhi,    // [cloud][b][n]
                 half8* __restrict__ fragBlo,
                 float* __restrict__ dsum_ws,    // [NBF] per-block |d| partials
                 float* __restrict__ out)
{
    int p = blockIdx.x * 256 + threadIdx.x;     // 0..65535
    if (p == 0) out[0] = 0.0f;                  // deterministic re-zero each call
    int c = p >> 15;
    int b = (p >> 13) & (BB - 1);
    int n = p & (NN - 1);

    const float* dp = (c ? target_disp : pred_disp) + (size_t)b * NN * 3;
    const float* tp = tmpl + (size_t)b * NN * 3;

    int n3 = n * 3;
    float dx = dp[n3 + 0], dy = dp[n3 + 1], dz = dp[n3 + 2];
    float x = tp[n3 + 0] + dx;
    float y = tp[n3 + 1] + dy;
    float z = tp[n3 + 2] + dz;
    float cc = fmaf(x, x, fmaf(y, y, z * z));

    // fused disp L1 partial (c==0 threads only; avoids double count)
    float s = 0.0f;
    if (c == 0) {
        const float* td = target_disp + (size_t)b * NN * 3;
        s = fabsf(dx - td[n3 + 0]) + fabsf(dy - td[n3 + 1]) + fabsf(dz - td[n3 + 2]);
    }

    _Float16 xh = (_Float16)x;  _Float16 xl = (_Float16)(x - (float)xh);
    _Float16 yh = (_Float16)y;  _Float16 yl = (_Float16)(y - (float)yh);
    _Float16 zh = (_Float16)z;  _Float16 zl = (_Float16)(z - (float)zh);
    _Float16 ch = (_Float16)cc; _Float16 cl = (_Float16)(cc - (float)ch);

    float ux = -2.0f * x, uy = -2.0f * y, uz = -2.0f * z;
    _Float16 uxh = (_Float16)ux; _Float16 uxl = (_Float16)(ux - (float)uxh);
    _Float16 uyh = (_Float16)uy; _Float16 uyl = (_Float16)(uy - (float)uyh);
    _Float16 uzh = (_Float16)uz; _Float16 uzl = (_Float16)(uz - (float)uzh);

    const _Float16 one  = (_Float16)1.0f;
    const _Float16 zero = (_Float16)0.0f;

    half8 aHi = {xh, yh, zh, xh, yh, zh, xl, yl};
    half8 aLo = {zl, ch, cl, one, one, zero, zero, zero};
    half8 bHi = {uxh, uyh, uzh, uxl, uyl, uzl, uxh, uyh};
    half8 bLo = {uzh, one, one, ch, cl, zero, zero, zero};

    fragA[(size_t)p * 2 + 0] = aHi;
    fragA[(size_t)p * 2 + 1] = aLo;
    fragBhi[p] = bHi;
    fragBlo[p] = bLo;

    // block-reduce s -> dsum_ws[blockIdx] (indexed write, no atomics/zeroing)
    for (int off = 32; off > 0; off >>= 1)
        s += __shfl_down(s, off, 64);
    __shared__ float ws4[4];
    int lane = threadIdx.x & 63, w = threadIdx.x >> 6;
    if (lane == 0) ws4[w] = s;
    __syncthreads();
    if (threadIdx.x == 0)
        dsum_ws[blockIdx.x] = ws4[0] + ws4[1] + ws4[2] + ws4[3];
}

__global__ __launch_bounds__(THREADS, 2)   // 256-reg budget: accs + prefetch in VGPRs
void chamfer_mfma(const half8* __restrict__ fragA,
                  const half8* __restrict__ fragBhi,
                  const half8* __restrict__ fragBlo,
                  float* __restrict__ rowpart)
{
    // 32 KB LDS: single staging buffer (reg-prefetch pipeline), reused as scratch
    __shared__ __align__(16) char lds_raw[32768];
    half8* sBhi = (half8*)lds_raw;            // 16 KB
    half8* sBlo = (half8*)(lds_raw + 16384);  // 16 KB

    int bx = blockIdx.x;
    int jq   = bx & (NJQ - 1);
    int iBlk = (bx >> 2) & (NIB - 1);
    int b    = (bx >> 7) & (BB - 1);
    int dir  = bx >> 9;
    int cA = dir, cB = dir ^ 1;

    const int tid  = threadIdx.x;
    const int lane = tid & 63;
    const int w    = tid >> 6;
    const int hi   = lane >> 5;
    const int li   = lane & 31;

    // ---- two A fragments per wave (rows i0, i0+32), loaded once ----
    int i0 = iBlk * IB + w * 64 + li;
    size_t aBase = ((size_t)cA * BB + b) * NN;
    half8 aF0 = fragA[(aBase + i0) * 2 + hi];
    half8 aF1 = fragA[(aBase + i0 + 32) * 2 + hi];

    size_t pB = ((size_t)cB * BB + b) * NN + (size_t)jq * (JR * NSTAGE);
    const half8* gHi = fragBhi + pB;
    const half8* gLo = fragBlo + pB;

    f32x16 kZero = {0.f,0.f,0.f,0.f, 0.f,0.f,0.f,0.f, 0.f,0.f,0.f,0.f, 0.f,0.f,0.f,0.f};
    float rm0[16], rm1[16];
    #pragma unroll
    for (int r = 0; r < 16; ++r) { rm0[r] = 1.0e30f; rm1[r] = 1.0e30f; }

    // ---- T14 pipeline: prefetch stage s+1 to regs during stage-s compute ----
    half8 pfHi[PFT], pfLo[PFT];
    // prologue: stage 0
    #pragma unroll
    for (int t = 0; t < PFT; ++t) {
        pfHi[t] = gHi[t * THREADS + tid];
        pfLo[t] = gLo[t * THREADS + tid];
    }
    #pragma unroll
    for (int t = 0; t < PFT; ++t) {
        sBhi[t * THREADS + tid] = pfHi[t];
        sBlo[t * THREADS + tid] = pfLo[t];
    }
    __syncthreads();

    for (int s = 0; s < NSTAGE; ++s) {
        // issue next stage's global loads (results unused until after barrier)
        if (s + 1 < NSTAGE) {
            const half8* srcHi = gHi + (size_t)(s + 1) * JR;
            const half8* srcLo = gLo + (size_t)(s + 1) * JR;
            #pragma unroll
            for (int t = 0; t < PFT; ++t) {
                pfHi[t] = srcHi[t * THREADS + tid];
                pfLo[t] = srcLo[t * THREADS + tid];
            }
        }

        const half8* baseB = hi ? sBlo : sBhi;
        // 1 ds_read feeds 2 MFMAs; dual plain-fmin chains (each fmin reads the
        // accumulator in place -- one acc-class operand per VALU op).
        #pragma unroll 4
        for (int c = 0; c < NCHUNK; ++c) {
            half8 b0 = baseB[c * 32 + li];
            f32x16 a0 = __builtin_amdgcn_mfma_f32_32x32x16_f16(aF0, b0, kZero, 0, 0, 0);
            f32x16 a1 = __builtin_amdgcn_mfma_f32_32x32x16_f16(aF1, b0, kZero, 0, 0, 0);
            #pragma unroll
            for (int r = 0; r < 16; ++r)
                rm0[r] = fminf(rm0[r], a0[r]);
            #pragma unroll
            for (int r = 0; r < 16; ++r)
                rm1[r] = fminf(rm1[r], a1[r]);
        }
        __syncthreads();   // all waves done reading before overwrite

        if (s + 1 < NSTAGE) {
            #pragma unroll
            for (int t = 0; t < PFT; ++t) {
                sBhi[t * THREADS + tid] = pfHi[t];
                sBlo[t * THREADS + tid] = pfLo[t];
            }
            __syncthreads();
        }
    }

    // ---- epilogue: two per-wave LDS-transpose passes, coalesced stores ----
    float* scr = (float*)lds_raw;
    int wbase = w * (32 * RSTRIDE);                 // per-wave 4608 B region
    int cbase = wbase + hi * 4 * RSTRIDE + li;
    size_t obase = ((size_t)(dir * BB + b) * NJQ + jq) * NN
                 + (size_t)iBlk * IB + w * 64;

    // pass 0: rows i0 block
    #pragma unroll
    for (int r = 0; r < 16; ++r)
        scr[cbase + ((r & 3) + 8 * (r >> 2)) * RSTRIDE] = rm0[r];
    __syncthreads();
    {
        const f32x4* rp = (const f32x4*)&scr[wbase + (lane & 31) * RSTRIDE];
        f32x4 q0 = rp[0], q1 = rp[1], q2 = rp[2], q3 = rp[3];
        f32x4 q4 = rp[4], q5 = rp[5], q6 = rp[6], q7 = rp[7];
        f32x4 m4;
        #pragma unroll
        for (int k = 0; k < 4; ++k)
            m4[k] = fminf(fminf(fminf(q0[k], q1[k]), fminf(q2[k], q3[k])),
                          fminf(fminf(q4[k], q5[k]), fminf(q6[k], q7[k])));
        float m = fminf(fminf(m4[0], m4[1]), fminf(m4[2], m4[3]));
        if (lane < 32) rowpart[obase + lane] = m;
    }
    __syncthreads();

    // pass 1: rows i0+32 block
    #pragma unroll
    for (int r = 0; r < 16; ++r)
        scr[cbase + ((r & 3) + 8 * (r >> 2)) * RSTRIDE] = rm1[r];
    __syncthreads();
    {
        const f32x4* rp = (const f32x4*)&scr[wbase + (lane & 31) * RSTRIDE];
        f32x4 q0 = rp[0], q1 = rp[1], q2 = rp[2], q3 = rp[3];
        f32x4 q4 = rp[4], q5 = rp[5], q6 = rp[6], q7 = rp[7];
        f32x4 m4;
        #pragma unroll
        for (int k = 0; k < 4; ++k)
            m4[k] = fminf(fminf(fminf(q0[k], q1[k]), fminf(q2[k], q3[k])),
                          fminf(fminf(q4[k], q5[k]), fminf(q6[k], q7[k])));
        float m = fminf(fminf(m4[0], m4[1]), fminf(m4[2], m4[3]));
        if (lane < 32) rowpart[obase + 32 + lane] = m;
    }
}

__global__ __launch_bounds__(256)
void final_reduce(const float* __restrict__ pred_mat,
                  const float* __restrict__ target_mat,
                  const float* __restrict__ rowpart,
                  const float* __restrict__ dsum_ws,
                  float* __restrict__ out)
{
    const int NROWS = 2 * BB * NN;   // 65536

    int gtid = blockIdx.x * blockDim.x + threadIdx.x;
    int gstride = gridDim.x * blockDim.x;

    float msum = 0.0f;
    for (int t = gtid; t < NROWS; t += gstride) {
        int db = t >> 13;            // dir*BB + b
        int i  = t & (NN - 1);
        const float* p = rowpart + (size_t)db * NJQ * NN + i;
        float m = 1.0e30f;
        #pragma unroll
        for (int jb = 0; jb < NJQ; ++jb)
            m = fminf(m, p[(size_t)jb * NN]);
        msum += fmaxf(m, 0.0f);      // clamp tiny negatives from dot-form
    }

    float acc = msum * (CD_W / (float)(BB * NN));

    if (gtid < NBF)
        acc += dsum_ws[gtid] * (DISP_W / (float)(BB * NN * 3));

    if (gtid < 2 * BB) {
        float d = pred_mat[gtid] - target_mat[gtid];
        acc += d * d * (MAT_W / (float)(2 * BB));
    }

    for (int off = 32; off > 0; off >>= 1)
        acc += __shfl_down(acc, off, 64);

    __shared__ float wsum[4];
    if ((threadIdx.x & 63) == 0) wsum[threadIdx.x >> 6] = acc;
    __syncthreads();
    if (threadIdx.x == 0)
        atomicAdd(out, wsum[0] + wsum[1] + wsum[2] + wsum[3]);
}

extern "C" void kernel_launch(void* const* d_in, const int* in_sizes, int n_in,
                              void* d_out, int out_size, void* d_ws, size_t ws_size,
                              hipStream_t stream) {
    const float* pred_disp   = (const float*)d_in[0];
    const float* pred_mat    = (const float*)d_in[1];
    const float* target_disp = (const float*)d_in[2];
    const float* target_mat  = (const float*)d_in[3];
    const float* tmpl        = (const float*)d_in[4];

    // ws layout:
    //   fragA   : NPTS*2 half8 = 2 MB
    //   fragBhi : NPTS   half8 = 1 MB
    //   fragBlo : NPTS   half8 = 1 MB
    //   rowpart : 2*BB*NJQ*NN floats = 1 MB (every slot written exactly once)
    //   dsum_ws : NBF floats               (every slot written exactly once)
    half8* fragA   = (half8*)d_ws;
    half8* fragBhi = fragA + (size_t)NPTS * 2;
    half8* fragBlo = fragBhi + NPTS;
    float* rowpart = (float*)(fragBlo + NPTS);
    float* dsum_ws = rowpart + (size_t)2 * BB * NJQ * NN;
    float* out = (float*)d_out;

    build_frags<<<NBF, 256, 0, stream>>>(pred_disp, target_disp, tmpl,
                                         fragA, fragBhi, fragBlo, dsum_ws, out);
    chamfer_mfma<<<GRID, THREADS, 0, stream>>>(fragA, fragBhi, fragBlo, rowpart);
    final_reduce<<<128, 256, 0, stream>>>(pred_mat, target_mat, rowpart, dsum_ws, out);
}